// Round 1
// baseline (1159.969 us; speedup 1.0000x reference)
//
#include <hip/hip_runtime.h>
#include <math.h>

#define DD 256
#define DHALF 128.0f
#define CSTRIDE 16777216u   /* 256^3 */
#define PLANE   65536u      /* 256^2 */

__global__ __launch_bounds__(256) void slice_extract_phase_kernel(
    const float* __restrict__ vol,   // (B, 2, D, D, D) float32
    const float* __restrict__ rot,   // (B, 3, 3) float32
    const float* __restrict__ trans, // (B, 2) float32
    float* __restrict__ out)         // (B, 2, D, D) float32
{
    // --- XCD-chunked block swizzle: XCD k (bid % 8) owns batch k's tiles in
    // row-major tile order, so concurrently-resident blocks on one XCD share
    // one volume's slab in that XCD's L2.
    const int bid = blockIdx.x;
    int sw;
    if ((gridDim.x & 7) == 0) {
        sw = (bid & 7) * (gridDim.x >> 3) + (bid >> 3);
    } else {
        sw = bid;
    }

    // 256 tiles of 16x16 px per batch image.
    const int tile = sw & 255;
    const int b    = sw >> 8;
    const int ti   = tile >> 4;      // tile row (i direction)
    const int tj   = tile & 15;      // tile col (j direction)

    // 4 waves per block in a 2x2 arrangement; each wave covers an 8x8 px patch
    // so one gather instruction's 64 addresses form a compact 3D blob instead
    // of a 64-long line.
    const int t = threadIdx.x;
    const int w = t >> 6;
    const int l = t & 63;
    const int i = (ti << 4) + ((w >> 1) << 3) + (l >> 3);
    const int j = (tj << 4) + ((w & 1) << 3) + (l & 7);

    // Rotation: columns 0 and 1 of R[b] (base z == 0). b is block-uniform ->
    // these compile to scalar loads.
    const float r00 = rot[b * 9 + 0];
    const float r01 = rot[b * 9 + 1];
    const float r10 = rot[b * 9 + 3];
    const float r11 = rot[b * 9 + 4];
    const float r20 = rot[b * 9 + 6];
    const float r21 = rot[b * 9 + 7];

    // i corresponds to reference gx (w axis), j to gy (h axis) -- same
    // (verified) semantics as the previous kernel.
    const float px = (float)i - DHALF;
    const float py = (float)j - DHALF;

    float x = fmaf(r00, px, fmaf(r01, py, DHALF));
    float y = fmaf(r10, px, fmaf(r11, py, DHALF));
    float z = fmaf(r20, px, fmaf(r21, py, DHALF));

    x = fminf(fmaxf(x, 0.0f), 255.0f);
    y = fminf(fmaxf(y, 0.0f), 255.0f);
    z = fminf(fmaxf(z, 0.0f), 255.0f);

    const float x0f = floorf(x), y0f = floorf(y), z0f = floorf(z);
    const float fx = x - x0f, fy = y - y0f, fz = z - z0f;
    const int x0 = (int)x0f, y0 = (int)y0f, z0 = (int)z0f;
    const int x1 = min(x0 + 1, DD - 1);
    const int y1 = min(y0 + 1, DD - 1);
    const int z1 = min(z0 + 1, DD - 1);

    const float gx0 = 1.0f - fx, gy0 = 1.0f - fy, gz0 = 1.0f - fz;
    const float w000 = gz0 * gy0 * gx0;
    const float w001 = gz0 * gy0 * fx;
    const float w010 = gz0 * fy * gx0;
    const float w011 = gz0 * fy * fx;
    const float w100 = fz * gy0 * gx0;
    const float w101 = fz * gy0 * fx;
    const float w110 = fz * fy * gx0;
    const float w111 = fz * fy * fx;

    // 32-bit offsets within one channel volume (67 MB < 4 GB); base pointers
    // are block-uniform -> SGPR base + single VGPR offset per load.
    const unsigned zo0 = (unsigned)z0 * PLANE, zo1 = (unsigned)z1 * PLANE;
    const unsigned yo0 = (unsigned)y0 * DD,    yo1 = (unsigned)y1 * DD;

    const unsigned o00 = zo0 + yo0;
    const unsigned o01 = zo0 + yo1;
    const unsigned o10 = zo1 + yo0;
    const unsigned o11 = zo1 + yo1;

    const float* __restrict__ v0 = vol + (size_t)b * (2u * CSTRIDE);
    const float* __restrict__ v1 = v0 + CSTRIDE;

    // Issue all 16 gathers before any arithmetic so they overlap.
    const float a000 = v0[o00 + x0], a001 = v0[o00 + x1];
    const float a010 = v0[o01 + x0], a011 = v0[o01 + x1];
    const float a100 = v0[o10 + x0], a101 = v0[o10 + x1];
    const float a110 = v0[o11 + x0], a111 = v0[o11 + x1];
    const float c000 = v1[o00 + x0], c001 = v1[o00 + x1];
    const float c010 = v1[o01 + x0], c011 = v1[o01 + x1];
    const float c100 = v1[o10 + x0], c101 = v1[o10 + x1];
    const float c110 = v1[o11 + x0], c111 = v1[o11 + x1];

    float re =
        a000 * w000 + a001 * w001 +
        a010 * w010 + a011 * w011 +
        a100 * w100 + a101 * w101 +
        a110 * w110 + a111 * w111;
    float im =
        c000 * w000 + c001 * w001 +
        c010 * w010 + c011 * w011 +
        c100 * w100 + c101 * w101 +
        c110 * w110 + c111 * w111;

    re *= 16.0f;   // sqrt(256)
    im *= 16.0f;

    // Phase shift: t0 = -trans[b,1]*128, t1 = -trans[b,0]*128
    const float t0 = -trans[b * 2 + 1] * DHALF;
    const float t1 = -trans[b * 2 + 0] * DHALF;
    const float ki = (float)i - DHALF;
    const float kj = (float)j - DHALF;
    const float ang = (-2.0f * (float)M_PI / 256.0f) * (t0 * ki + t1 * kj);

    float sn, cs;
    sincosf(ang, &sn, &cs);   // accurate version: |ang| can reach ~800 rad

    const size_t ob = (size_t)b * 2 * PLANE + (size_t)i * DD + j;
    out[ob]         = re * cs - im * sn;
    out[ob + PLANE] = re * sn + im * cs;
}

extern "C" void kernel_launch(void* const* d_in, const int* in_sizes, int n_in,
                              void* d_out, int out_size, void* d_ws, size_t ws_size,
                              hipStream_t stream) {
    const float* vol   = (const float*)d_in[0];
    const float* rot   = (const float*)d_in[1];
    const float* trans = (const float*)d_in[2];
    float* out = (float*)d_out;

    const int B = in_sizes[0] / (2 * DD * DD * DD);   // 8
    const int total = B * DD * DD;                    // 524288 threads
    dim3 block(256);
    dim3 grid(total / 256);                           // 2048 blocks
    slice_extract_phase_kernel<<<grid, block, 0, stream>>>(vol, rot, trans, out);
}